// Round 12
// baseline (134.853 us; speedup 1.0000x reference)
//
#include <hip/hip_runtime.h>

#define Bsz 32
#define Nn  1024
#define Ff  128

// INSTRUMENTED ROUND 2: r10 kernel verbatim, but gemm2 body x3 (idempotent
// reps, memory-clobber fences) so gemm2 exceeds the ~84us harness-fill floor
// and appears in top-5 rocprof rows with full counters. Output identical.

typedef __attribute__((ext_vector_type(8))) short bf16x8;
typedef __attribute__((ext_vector_type(4))) float f32x4;

static __device__ inline short f2bf(float f) {
    unsigned u = __builtin_bit_cast(unsigned, f);
    unsigned r = u + 0x7FFFu + ((u >> 16) & 1u);
    return (short)(r >> 16);
}
static __device__ inline unsigned pack2(float lo, float hi) {
    return (unsigned)(unsigned short)f2bf(lo) | ((unsigned)(unsigned short)f2bf(hi) << 16);
}

__global__ __launch_bounds__(256) void k1_fused_wt(
    const float* __restrict__ feats,
    const float* __restrict__ w,
    float* __restrict__ out_feats,
    short* __restrict__ fb,
    short* __restrict__ vw)
{
    __shared__ short wT_lds[128 * 128];   // 32 KB, [g][k] bf16, swizzled

    const int tid  = threadIdx.x;
    const int wid  = tid >> 6;
    const int lane = tid & 63;
    const int lr = lane & 15;
    const int kg = lane >> 4;

    {
        const int g    = tid >> 1;
        const int kb   = (tid & 1) * 64;
        const int swzg = (g & 7) << 4;
        const size_t gofs = (size_t)g;
        for (int kk = 0; kk < 64; kk += 2) {
            int k = kb + kk;
            float lo = w[(size_t)k * Ff + gofs];
            float hi = w[(size_t)(k + 1) * Ff + gofs];
            unsigned pk = pack2(lo, hi);
            *(unsigned*)((char*)wT_lds + (g << 8) + ((k * 2) ^ swzg)) = pk;
        }
    }

    const int row0  = blockIdx.x * 64;
    const int myrow = row0 + wid * 16 + lr;
    const float* frow = feats + (size_t)myrow * Ff;
    float* orow       = out_feats + (size_t)myrow * Ff;
    short* brow       = fb + (size_t)myrow * Ff;

    bf16x8 a[4];
    for (int kc = 0; kc < 4; ++kc) {
        int k0 = kc * 32 + kg * 8;
        f32x4 v0 = ((const f32x4*)(frow + k0))[0];
        f32x4 v1 = ((const f32x4*)(frow + k0))[1];
        __builtin_nontemporal_store(v0, (f32x4*)(orow + k0));
        __builtin_nontemporal_store(v1, (f32x4*)(orow + k0) + 1);
        a[kc] = (bf16x8){ f2bf(v0[0]), f2bf(v0[1]), f2bf(v0[2]), f2bf(v0[3]),
                          f2bf(v1[0]), f2bf(v1[1]), f2bf(v1[2]), f2bf(v1[3]) };
        *((bf16x8*)(brow + k0)) = a[kc];
    }
    __syncthreads();

    f32x4 acc[8] = {};
    const int swz = (lr & 7) << 4;
    for (int kc = 0; kc < 4; ++kc) {
        const int kbyte = kc * 64 + kg * 16;
        for (int nf = 0; nf < 8; ++nf) {
            const int row = nf * 16 + lr;
            bf16x8 b = *(const bf16x8*)((char*)wT_lds + (row << 8) + (kbyte ^ swz));
            acc[nf] = __builtin_amdgcn_mfma_f32_16x16x32_bf16(a[kc], b, acc[nf], 0, 0, 0);
        }
    }

    for (int nf = 0; nf < 8; ++nf) {
        int g = nf * 16 + lr;
        for (int r = 0; r < 4; ++r)
            vw[(size_t)(row0 + wid * 16 + kg * 4 + r) * Ff + g] = f2bf(acc[nf][r]);
    }
}

__global__ __launch_bounds__(256) void gemm2_x3(
    const short* __restrict__ vw,     // [B, N, F] bf16
    const short* __restrict__ fb,     // [B, N, F] bf16
    const float* __restrict__ bias,
    float* __restrict__ y)            // [B, N, N]
{
    int blk   = blockIdx.x;
    int xcd   = blk & 7;
    int q     = blk >> 3;
    int chunk = q >> 4;
    int k     = q & 15;
    int super_id = chunk * 8 + xcd;
    int bidx  = super_id >> 2;
    int s     = super_id & 3;
    int sm = s >> 1, sn = s & 1;
    int mt = sm * 4 + (k >> 2);
    int nt = sn * 4 + (k & 3);

    int tid = threadIdx.x;
    int wid = tid >> 6, lane = tid & 63;
    int wm = wid >> 1, wn = wid & 1;
    int lr = lane & 15, kg = lane >> 4;

    for (int rep = 0; rep < 3; ++rep) {
        asm volatile("" ::: "memory");
        const short* A  = vw + (size_t)bidx * Nn * Ff;
        const short* Bp = fb + (size_t)bidx * Nn * Ff;
        int am0 = mt * 128 + wm * 64;
        int bn0 = nt * 128 + wn * 64;

        f32x4 acc[4][4] = {};

        for (int kc = 0; kc < 4; ++kc) {
            int k0 = kc * 32 + kg * 8;
            bf16x8 a[4], b[4];
            for (int mf = 0; mf < 4; ++mf)
                a[mf] = *((const bf16x8*)(A + (size_t)(am0 + mf * 16 + lr) * Ff + k0));
            for (int nf = 0; nf < 4; ++nf)
                b[nf] = *((const bf16x8*)(Bp + (size_t)(bn0 + nf * 16 + lr) * Ff + k0));
            for (int mf = 0; mf < 4; ++mf)
                for (int nf = 0; nf < 4; ++nf)
                    acc[mf][nf] = __builtin_amdgcn_mfma_f32_16x16x32_bf16(
                        a[mf], b[nf], acc[mf][nf], 0, 0, 0);
        }

        float bv = bias[0];
        float* Y = y + (size_t)bidx * Nn * Nn;
        for (int mf = 0; mf < 4; ++mf) {
            int row = am0 + mf * 16 + kg * 4;
            for (int nf = 0; nf < 4; ++nf) {
                int col = bn0 + nf * 16 + lr;
                float* p = Y + (size_t)row * Nn + col;
                for (int r = 0; r < 4; ++r)
                    __builtin_nontemporal_store(acc[mf][nf][r] + bv, p + (size_t)r * Nn);
            }
        }
    }
}

extern "C" void kernel_launch(void* const* d_in, const int* in_sizes, int n_in,
                              void* d_out, int out_size, void* d_ws, size_t ws_size,
                              hipStream_t stream) {
    const float* feats = (const float*)d_in[1];
    const float* w     = (const float*)d_in[2];
    const float* bias  = (const float*)d_in[3];
    float* y = (float*)d_out;
    float* out_feats = y + (size_t)Bsz * Nn * Nn;

    short* vw = (short*)d_ws;
    short* fb = vw + (size_t)Bsz * Nn * Ff;

    k1_fused_wt<<<512, 256, 0, stream>>>(feats, w, out_feats, fb, vw);
    gemm2_x3<<<2048, 256, 0, stream>>>(vw, fb, bias, y);
}

// Round 13
// 58.941 us; speedup vs baseline: 2.2879x; 2.2879x over previous
//
#include <hip/hip_runtime.h>

#define Bsz 32
#define Nn  1024
#define Ff  128

typedef __attribute__((ext_vector_type(8))) short bf16x8;
typedef __attribute__((ext_vector_type(4))) float f32x4;

// round-to-nearest-even f32 -> bf16 (bit pattern as short)
static __device__ inline short f2bf(float f) {
    unsigned u = __builtin_bit_cast(unsigned, f);
    unsigned r = u + 0x7FFFu + ((u >> 16) & 1u);
    return (short)(r >> 16);
}
static __device__ inline unsigned pack2(float lo, float hi) {
    return (unsigned)(unsigned short)f2bf(lo) | ((unsigned)(unsigned short)f2bf(hi) << 16);
}

// ---------------------------------------------------------------------------
// k1_fused_wt: VERBATIM r10 (passed, 65.2).
// ---------------------------------------------------------------------------
__global__ __launch_bounds__(256) void k1_fused_wt(
    const float* __restrict__ feats,
    const float* __restrict__ w,
    float* __restrict__ out_feats,
    short* __restrict__ fb,
    short* __restrict__ vw)
{
    __shared__ short wT_lds[128 * 128];   // 32 KB, [g][k] bf16, swizzled

    const int tid  = threadIdx.x;
    const int wid  = tid >> 6;
    const int lane = tid & 63;
    const int lr = lane & 15;
    const int kg = lane >> 4;

    {
        const int g    = tid >> 1;
        const int kb   = (tid & 1) * 64;
        const int swzg = (g & 7) << 4;
        const size_t gofs = (size_t)g;
        for (int kk = 0; kk < 64; kk += 2) {
            int k = kb + kk;
            float lo = w[(size_t)k * Ff + gofs];
            float hi = w[(size_t)(k + 1) * Ff + gofs];
            unsigned pk = pack2(lo, hi);
            *(unsigned*)((char*)wT_lds + (g << 8) + ((k * 2) ^ swzg)) = pk;
        }
    }

    const int row0  = blockIdx.x * 64;
    const int myrow = row0 + wid * 16 + lr;
    const float* frow = feats + (size_t)myrow * Ff;
    float* orow       = out_feats + (size_t)myrow * Ff;
    short* brow       = fb + (size_t)myrow * Ff;

    bf16x8 a[4];
    for (int kc = 0; kc < 4; ++kc) {
        int k0 = kc * 32 + kg * 8;
        f32x4 v0 = ((const f32x4*)(frow + k0))[0];
        f32x4 v1 = ((const f32x4*)(frow + k0))[1];
        __builtin_nontemporal_store(v0, (f32x4*)(orow + k0));
        __builtin_nontemporal_store(v1, (f32x4*)(orow + k0) + 1);
        a[kc] = (bf16x8){ f2bf(v0[0]), f2bf(v0[1]), f2bf(v0[2]), f2bf(v0[3]),
                          f2bf(v1[0]), f2bf(v1[1]), f2bf(v1[2]), f2bf(v1[3]) };
        *((bf16x8*)(brow + k0)) = a[kc];
    }
    __syncthreads();

    f32x4 acc[8] = {};
    const int swz = (lr & 7) << 4;
    for (int kc = 0; kc < 4; ++kc) {
        const int kbyte = kc * 64 + kg * 16;
        for (int nf = 0; nf < 8; ++nf) {
            const int row = nf * 16 + lr;
            bf16x8 b = *(const bf16x8*)((char*)wT_lds + (row << 8) + (kbyte ^ swz));
            acc[nf] = __builtin_amdgcn_mfma_f32_16x16x32_bf16(a[kc], b, acc[nf], 0, 0, 0);
        }
    }

    for (int nf = 0; nf < 8; ++nf) {
        int g = nf * 16 + lr;
        for (int r = 0; r < 4; ++r)
            vw[(size_t)(row0 + wid * 16 + kg * 4 + r) * Ff + g] = f2bf(acc[nf][r]);
    }
}

// ---------------------------------------------------------------------------
// gemm2: r10 main loop + super-tile decode VERBATIM. NEW epilogue: per-wave
// LDS transpose (r2 retry, now with __syncthreads between LDS writes and
// vector reads). Each store inst: 4 rows x 256B contiguous = full 128B
// lines, 1024B/inst (the fill-kernel pattern) -> kills the 1.32x write
// amplification and the 4.3-vs-7.2 TB/s write-efficiency gap seen in r12.
// ---------------------------------------------------------------------------
__global__ __launch_bounds__(256) void gemm2_kernel(
    const short* __restrict__ vw,     // [B, N, F] bf16
    const short* __restrict__ fb,     // [B, N, F] bf16
    const float* __restrict__ bias,
    float* __restrict__ y)            // [B, N, N]
{
    __shared__ float tbuf[4][16 * 68];   // per-wave 16x64 f32 tile, pad 68

    int blk   = blockIdx.x;
    int xcd   = blk & 7;
    int q     = blk >> 3;
    int chunk = q >> 4;
    int k     = q & 15;
    int super_id = chunk * 8 + xcd;
    int bidx  = super_id >> 2;
    int s     = super_id & 3;
    int sm = s >> 1, sn = s & 1;
    int mt = sm * 4 + (k >> 2);
    int nt = sn * 4 + (k & 3);

    int tid = threadIdx.x;
    int wid = tid >> 6, lane = tid & 63;
    int wm = wid >> 1, wn = wid & 1;
    int lr = lane & 15, kg = lane >> 4;

    const short* A  = vw + (size_t)bidx * Nn * Ff;
    const short* Bp = fb + (size_t)bidx * Nn * Ff;
    int am0 = mt * 128 + wm * 64;
    int bn0 = nt * 128 + wn * 64;

    f32x4 acc[4][4] = {};

    for (int kc = 0; kc < 4; ++kc) {
        int k0 = kc * 32 + kg * 8;
        bf16x8 a[4], b[4];
        for (int mf = 0; mf < 4; ++mf)
            a[mf] = *((const bf16x8*)(A + (size_t)(am0 + mf * 16 + lr) * Ff + k0));
        for (int nf = 0; nf < 4; ++nf)
            b[nf] = *((const bf16x8*)(Bp + (size_t)(bn0 + nf * 16 + lr) * Ff + k0));
        for (int mf = 0; mf < 4; ++mf)
            for (int nf = 0; nf < 4; ++nf)
                acc[mf][nf] = __builtin_amdgcn_mfma_f32_16x16x32_bf16(
                    a[mf], b[nf], acc[mf][nf], 0, 0, 0);
    }

    const float bv = bias[0];
    float* Y = y + (size_t)bidx * Nn * Nn;
    float* L = tbuf[wid];
    const int c4 = (lane & 15) * 4;

    for (int mf = 0; mf < 4; ++mf) {
        // C-fragment layout: col = lane&15 (lr), row = kg*4 + r
        for (int nf = 0; nf < 4; ++nf)
            for (int r = 0; r < 4; ++r)
                L[(kg * 4 + r) * 68 + nf * 16 + lr] = acc[mf][nf][r] + bv;
        __syncthreads();
        // read back transposed: lane -> (row = rg*4 + kg, 16B at col c4)
        for (int rg = 0; rg < 4; ++rg) {
            int rl = rg * 4 + kg;
            f32x4 v = *((const f32x4*)&L[rl * 68 + c4]);
            __builtin_nontemporal_store(
                v, (f32x4*)(Y + (size_t)(am0 + mf * 16 + rl) * Nn + bn0 + c4));
        }
        __syncthreads();
    }
}

extern "C" void kernel_launch(void* const* d_in, const int* in_sizes, int n_in,
                              void* d_out, int out_size, void* d_ws, size_t ws_size,
                              hipStream_t stream) {
    const float* feats = (const float*)d_in[1];
    const float* w     = (const float*)d_in[2];
    const float* bias  = (const float*)d_in[3];
    float* y = (float*)d_out;
    float* out_feats = y + (size_t)Bsz * Nn * Nn;

    short* vw = (short*)d_ws;
    short* fb = vw + (size_t)Bsz * Nn * Ff;

    k1_fused_wt<<<512, 256, 0, stream>>>(feats, w, out_feats, fb, vw);
    gemm2_kernel<<<2048, 256, 0, stream>>>(vw, fb, bias, y);
}

// Round 14
// 55.743 us; speedup vs baseline: 2.4192x; 1.0574x over previous
//
#include <hip/hip_runtime.h>

#define Bsz 32
#define Nn  1024
#define Ff  128

typedef __attribute__((ext_vector_type(8))) short bf16x8;
typedef __attribute__((ext_vector_type(4))) float f32x4;

// round-to-nearest-even f32 -> bf16 (bit pattern as short)
static __device__ inline short f2bf(float f) {
    unsigned u = __builtin_bit_cast(unsigned, f);
    unsigned r = u + 0x7FFFu + ((u >> 16) & 1u);
    return (short)(r >> 16);
}
static __device__ inline unsigned pack2(float lo, float hi) {
    return (unsigned)(unsigned short)f2bf(lo) | ((unsigned)(unsigned short)f2bf(hi) << 16);
}

// ---------------------------------------------------------------------------
// k1_fused_wt: VERBATIM r10/r13 (k1 ~7 us, near its traffic floor).
// ---------------------------------------------------------------------------
__global__ __launch_bounds__(256) void k1_fused_wt(
    const float* __restrict__ feats,
    const float* __restrict__ w,
    float* __restrict__ out_feats,
    short* __restrict__ fb,
    short* __restrict__ vw)
{
    __shared__ short wT_lds[128 * 128];   // 32 KB, [g][k] bf16, swizzled

    const int tid  = threadIdx.x;
    const int wid  = tid >> 6;
    const int lane = tid & 63;
    const int lr = lane & 15;
    const int kg = lane >> 4;

    {
        const int g    = tid >> 1;
        const int kb   = (tid & 1) * 64;
        const int swzg = (g & 7) << 4;
        const size_t gofs = (size_t)g;
        for (int kk = 0; kk < 64; kk += 2) {
            int k = kb + kk;
            float lo = w[(size_t)k * Ff + gofs];
            float hi = w[(size_t)(k + 1) * Ff + gofs];
            unsigned pk = pack2(lo, hi);
            *(unsigned*)((char*)wT_lds + (g << 8) + ((k * 2) ^ swzg)) = pk;
        }
    }

    const int row0  = blockIdx.x * 64;
    const int myrow = row0 + wid * 16 + lr;
    const float* frow = feats + (size_t)myrow * Ff;
    float* orow       = out_feats + (size_t)myrow * Ff;
    short* brow       = fb + (size_t)myrow * Ff;

    bf16x8 a[4];
    for (int kc = 0; kc < 4; ++kc) {
        int k0 = kc * 32 + kg * 8;
        f32x4 v0 = ((const f32x4*)(frow + k0))[0];
        f32x4 v1 = ((const f32x4*)(frow + k0))[1];
        __builtin_nontemporal_store(v0, (f32x4*)(orow + k0));
        __builtin_nontemporal_store(v1, (f32x4*)(orow + k0) + 1);
        a[kc] = (bf16x8){ f2bf(v0[0]), f2bf(v0[1]), f2bf(v0[2]), f2bf(v0[3]),
                          f2bf(v1[0]), f2bf(v1[1]), f2bf(v1[2]), f2bf(v1[3]) };
        *((bf16x8*)(brow + k0)) = a[kc];
    }
    __syncthreads();

    f32x4 acc[8] = {};
    const int swz = (lr & 7) << 4;
    for (int kc = 0; kc < 4; ++kc) {
        const int kbyte = kc * 64 + kg * 16;
        for (int nf = 0; nf < 8; ++nf) {
            const int row = nf * 16 + lr;
            bf16x8 b = *(const bf16x8*)((char*)wT_lds + (row << 8) + (kbyte ^ swz));
            acc[nf] = __builtin_amdgcn_mfma_f32_16x16x32_bf16(a[kc], b, acc[nf], 0, 0, 0);
        }
    }

    for (int nf = 0; nf < 8; ++nf) {
        int g = nf * 16 + lr;
        for (int r = 0; r < 4; ++r)
            vw[(size_t)(row0 + wid * 16 + kg * 4 + r) * Ff + g] = f2bf(acc[nf][r]);
    }
}

// ---------------------------------------------------------------------------
// gemm2: r13 main loop + super-tile decode VERBATIM. Epilogue changes only:
//  - NO __syncthreads (transpose buffer is per-wave private; r13's 8
//    block-wide barriers synchronized all waves' phases -> bursty writes)
//  - per-wave DOUBLE-BUFFERED 16x68 tile ([wid][mf&1]) so there is no WAR
//    hazard on the next mf; intra-wave write->read ordering via
//    __threadfence_block() (compiler+HW fence, kills the r2 reorder risk)
//  - __launch_bounds__(256,4): cap 128 VGPR -> 4 blocks/CU (+33% TLP)
// ---------------------------------------------------------------------------
__global__ __launch_bounds__(256, 4) void gemm2_kernel(
    const short* __restrict__ vw,     // [B, N, F] bf16
    const short* __restrict__ fb,     // [B, N, F] bf16
    const float* __restrict__ bias,
    float* __restrict__ y)            // [B, N, N]
{
    __shared__ float tbuf[4][2][16 * 68];   // per-wave double-buffered tile

    int blk   = blockIdx.x;
    int xcd   = blk & 7;
    int q     = blk >> 3;
    int chunk = q >> 4;
    int k     = q & 15;
    int super_id = chunk * 8 + xcd;
    int bidx  = super_id >> 2;
    int s     = super_id & 3;
    int sm = s >> 1, sn = s & 1;
    int mt = sm * 4 + (k >> 2);
    int nt = sn * 4 + (k & 3);

    int tid = threadIdx.x;
    int wid = tid >> 6, lane = tid & 63;
    int wm = wid >> 1, wn = wid & 1;
    int lr = lane & 15, kg = lane >> 4;

    const short* A  = vw + (size_t)bidx * Nn * Ff;
    const short* Bp = fb + (size_t)bidx * Nn * Ff;
    int am0 = mt * 128 + wm * 64;
    int bn0 = nt * 128 + wn * 64;

    f32x4 acc[4][4] = {};

    for (int kc = 0; kc < 4; ++kc) {
        int k0 = kc * 32 + kg * 8;
        bf16x8 a[4], b[4];
        for (int mf = 0; mf < 4; ++mf)
            a[mf] = *((const bf16x8*)(A + (size_t)(am0 + mf * 16 + lr) * Ff + k0));
        for (int nf = 0; nf < 4; ++nf)
            b[nf] = *((const bf16x8*)(Bp + (size_t)(bn0 + nf * 16 + lr) * Ff + k0));
        for (int mf = 0; mf < 4; ++mf)
            for (int nf = 0; nf < 4; ++nf)
                acc[mf][nf] = __builtin_amdgcn_mfma_f32_16x16x32_bf16(
                    a[mf], b[nf], acc[mf][nf], 0, 0, 0);
    }

    const float bv = bias[0];
    float* Y = y + (size_t)bidx * Nn * Nn;
    const int c4 = lr * 4;

    for (int mf = 0; mf < 4; ++mf) {
        float* L = tbuf[wid][mf & 1];
        // C-fragment layout: col = lr, row = kg*4 + r
        for (int nf = 0; nf < 4; ++nf)
            for (int r = 0; r < 4; ++r)
                L[(kg * 4 + r) * 68 + nf * 16 + lr] = acc[mf][nf][r] + bv;
        __threadfence_block();   // order LDS writes before the vector reads
        // read back transposed: lane -> (row = rg*4 + kg, 16B at col c4)
        for (int rg = 0; rg < 4; ++rg) {
            int rl = rg * 4 + kg;
            f32x4 v = *((const f32x4*)&L[rl * 68 + c4]);
            __builtin_nontemporal_store(
                v, (f32x4*)(Y + (size_t)(am0 + mf * 16 + rl) * Nn + bn0 + c4));
        }
    }
}

extern "C" void kernel_launch(void* const* d_in, const int* in_sizes, int n_in,
                              void* d_out, int out_size, void* d_ws, size_t ws_size,
                              hipStream_t stream) {
    const float* feats = (const float*)d_in[1];
    const float* w     = (const float*)d_in[2];
    const float* bias  = (const float*)d_in[3];
    float* y = (float*)d_out;
    float* out_feats = y + (size_t)Bsz * Nn * Nn;

    short* vw = (short*)d_ws;
    short* fb = vw + (size_t)Bsz * Nn * Ff;

    k1_fused_wt<<<512, 256, 0, stream>>>(feats, w, out_feats, fb, vw);
    gemm2_kernel<<<2048, 256, 0, stream>>>(vw, fb, bias, y);
}